// Round 1
// baseline (825.816 us; speedup 1.0000x reference)
//
#include <hip/hip_runtime.h>

#define N_NODES 100000
#define N_EDGES 1600000
#define D 64
#define NB 391                 // buckets of 256 rows
#define BCAP 4480              // bucket capacity (mean 4093, sigma 64 -> z=6)
#define PBLK 256               // scatter blocks
#define TPB 512                // scatter/accum threads per block
#define CHUNK ((N_EDGES + PBLK - 1) / PBLK)   // 6250 edges per block
#define CURSTRIDE 32           // pad cursors to one line each

__device__ __forceinline__ unsigned short f2b(float f) {
    unsigned u = __float_as_uint(f);
    u += 0x7FFF + ((u >> 16) & 1);            // round-to-nearest-even
    return (unsigned short)(u >> 16);
}
__device__ __forceinline__ float b2f(unsigned short v) {
    return __uint_as_float(((unsigned)v) << 16);
}

// ---- pass 0: cursors start at each bucket's base ----
__global__ void init_cursor_kernel(int* __restrict__ cursor) {
    int b = blockIdx.x * blockDim.x + threadIdx.x;
    if (b < NB) cursor[b * CURSTRIDE] = b * BCAP;
}

// ---- pass 1: fused count+partition. LDS hist -> reserve runs -> write epack ----
// (unchanged from the verified kernel)
__global__ void scatter_direct_kernel(const int* __restrict__ ei, int* __restrict__ cursor,
                                      int* __restrict__ epack) {
    __shared__ int h[NB];
    __shared__ int lbase[NB];
    __shared__ int lcur[NB];
    int t = threadIdx.x;
    for (int i = t; i < NB; i += TPB) h[i] = 0;
    __syncthreads();
    int s = blockIdx.x * CHUNK;
    int e = min(s + CHUNK, N_EDGES);
    for (int i = s + t; i < e; i += TPB) {
        int r = ei[i], c = ei[N_EDGES + i];
        if (r != c) atomicAdd(&h[r >> 8], 1);
    }
    __syncthreads();
    for (int i = t; i < NB; i += TPB) {
        lbase[i] = atomicAdd(&cursor[i * CURSTRIDE], h[i]);  // reserve contiguous run
        lcur[i] = 0;
    }
    __syncthreads();
    for (int i = s + t; i < e; i += TPB) {   // chunk is L2-hot from pass A
        int r = ei[i], c = ei[N_EDGES + i];
        if (r != c) {
            int b = r >> 8;
            int p = lbase[b] + atomicAdd(&lcur[b], 1);
            epack[p] = ((r & 255) << 17) | c;
        }
    }
}

// ---- pass 2: per-bucket histogram -> dinv -> fused bf16 convert. NO SORT. ----
__global__ void hist_convert_kernel(const int* __restrict__ cursor, const int* __restrict__ epack,
                                    float* __restrict__ dinv, const float* __restrict__ x,
                                    unsigned short* __restrict__ xs) {
    __shared__ int h[256];
    __shared__ float dv[256];
    int b = blockIdx.x;
    int t = threadIdx.x;
    int base = b * BCAP;
    int n = min(cursor[b * CURSTRIDE] - base, BCAP);
    h[t] = 0;
    __syncthreads();
    for (int i = t; i < n; i += 256) atomicAdd(&h[epack[base + i] >> 17], 1);
    __syncthreads();
    int row = b * 256 + t;
    float di = rsqrtf((float)(1 + h[t]));     // deg = nonself-count + 1 (self loop)
    if (row < N_NODES) dinv[row] = di;
    dv[t] = di;
    __syncthreads();
    // fused convert for this bucket's rows: xs = bf16(x * dinv)
    int nrows = min(256, N_NODES - b * 256);
    const float4* x4 = (const float4*)x;
    ushort4* xs4 = (ushort4*)xs;
    for (int i = t; i < nrows * 16; i += 256) {   // 16 float4 per row
        int rl = i >> 4;
        float4 vv = x4[(size_t)(b * 256 + rl) * 16 + (i & 15)];
        float dd = dv[rl];
        ushort4 o;
        o.x = f2b(vv.x * dd);
        o.y = f2b(vv.y * dd);
        o.z = f2b(vv.z * dd);
        o.w = f2b(vv.w * dd);
        xs4[(size_t)(b * 256 + rl) * 16 + (i & 15)] = o;
    }
}

// ---- pass 3: bucket accumulate. 64KB LDS f32 acc, ds_add_f32 per edge. ----
// lane d = feature d; shfl-broadcast edge words; MLP-8 on the random xs row reads.
__global__ __launch_bounds__(TPB) void accum_kernel(const int* __restrict__ cursor,
                                                    const int* __restrict__ epack,
                                                    const unsigned short* __restrict__ xs,
                                                    const float* __restrict__ dinv,
                                                    float* __restrict__ out) {
    __shared__ float acc[256 * D];           // 64 KB -> 2 blocks/CU
    int b = blockIdx.x;
    int t = threadIdx.x;
    int base = b * BCAP;
    int n = min(cursor[b * CURSTRIDE] - base, BCAP);
    int nrows = min(256, N_NODES - b * 256);
    // init with the self-loop term: acc[r][d] = xs[r][d] (xs already carries dinv[r])
    for (int i = t; i < 256 * D; i += TPB)
        acc[i] = (i < nrows * D) ? b2f(xs[(size_t)b * 256 * D + i]) : 0.0f;
    __syncthreads();
    int wid = t >> 6, lane = t & 63;
    for (int j = wid * 64; j < n; j += TPB) {
        int idx = j + lane;
        int ej = (idx < n) ? epack[base + idx] : 0;
        int m = min(64, n - j);
        int k = 0;
        for (; k + 8 <= m; k += 8) {
            int e0 = __shfl(ej, k);
            int e1 = __shfl(ej, k + 1);
            int e2 = __shfl(ej, k + 2);
            int e3 = __shfl(ej, k + 3);
            int e4 = __shfl(ej, k + 4);
            int e5 = __shfl(ej, k + 5);
            int e6 = __shfl(ej, k + 6);
            int e7 = __shfl(ej, k + 7);
            float v0 = b2f(xs[(e0 & 0x1FFFF) * D + lane]);   // 8 independent 128B loads
            float v1 = b2f(xs[(e1 & 0x1FFFF) * D + lane]);
            float v2 = b2f(xs[(e2 & 0x1FFFF) * D + lane]);
            float v3 = b2f(xs[(e3 & 0x1FFFF) * D + lane]);
            float v4 = b2f(xs[(e4 & 0x1FFFF) * D + lane]);
            float v5 = b2f(xs[(e5 & 0x1FFFF) * D + lane]);
            float v6 = b2f(xs[(e6 & 0x1FFFF) * D + lane]);
            float v7 = b2f(xs[(e7 & 0x1FFFF) * D + lane]);
            atomicAdd(&acc[((e0 >> 17) << 6) | lane], v0);   // ds_add_f32, banks 2-way = free
            atomicAdd(&acc[((e1 >> 17) << 6) | lane], v1);
            atomicAdd(&acc[((e2 >> 17) << 6) | lane], v2);
            atomicAdd(&acc[((e3 >> 17) << 6) | lane], v3);
            atomicAdd(&acc[((e4 >> 17) << 6) | lane], v4);
            atomicAdd(&acc[((e5 >> 17) << 6) | lane], v5);
            atomicAdd(&acc[((e6 >> 17) << 6) | lane], v6);
            atomicAdd(&acc[((e7 >> 17) << 6) | lane], v7);
        }
        for (; k + 4 <= m; k += 4) {
            int e0 = __shfl(ej, k);
            int e1 = __shfl(ej, k + 1);
            int e2 = __shfl(ej, k + 2);
            int e3 = __shfl(ej, k + 3);
            float v0 = b2f(xs[(e0 & 0x1FFFF) * D + lane]);
            float v1 = b2f(xs[(e1 & 0x1FFFF) * D + lane]);
            float v2 = b2f(xs[(e2 & 0x1FFFF) * D + lane]);
            float v3 = b2f(xs[(e3 & 0x1FFFF) * D + lane]);
            atomicAdd(&acc[((e0 >> 17) << 6) | lane], v0);
            atomicAdd(&acc[((e1 >> 17) << 6) | lane], v1);
            atomicAdd(&acc[((e2 >> 17) << 6) | lane], v2);
            atomicAdd(&acc[((e3 >> 17) << 6) | lane], v3);
        }
        for (; k < m; k++) {
            int e = __shfl(ej, k);
            atomicAdd(&acc[((e >> 17) << 6) | lane], b2f(xs[(e & 0x1FFFF) * D + lane]));
        }
    }
    __syncthreads();
    // epilogue: out[r] = dinv[r] * acc[r]
    for (int i = t; i < nrows * D; i += TPB) {
        int r = b * 256 + (i >> 6);
        out[(size_t)r * D + (i & 63)] = dinv[r] * acc[i];
    }
}

extern "C" void kernel_launch(void* const* d_in, const int* in_sizes, int n_in,
                              void* d_out, int out_size, void* d_ws, size_t ws_size,
                              hipStream_t stream) {
    const float* x = (const float*)d_in[0];
    const int* ei = (const int*)d_in[1];
    float* out = (float*)d_out;

    // workspace (~20.2 MB): cursor | dinv | epack | xs
    int* cursor = (int*)d_ws;                                  // [NB*CURSTRIDE]
    float* dinv = (float*)(cursor + NB * CURSTRIDE);           // [N_NODES]
    int* epack = (int*)(dinv + N_NODES);                       // [NB*BCAP]
    unsigned short* xs = (unsigned short*)(epack + NB * BCAP); // [N_NODES*D]

    init_cursor_kernel<<<(NB + 255) / 256, 256, 0, stream>>>(cursor);
    scatter_direct_kernel<<<PBLK, TPB, 0, stream>>>(ei, cursor, epack);
    hist_convert_kernel<<<NB, 256, 0, stream>>>(cursor, epack, dinv, x, xs);
    accum_kernel<<<NB, TPB, 0, stream>>>(cursor, epack, xs, dinv, out);
}

// Round 2
// 333.257 us; speedup vs baseline: 2.4780x; 2.4780x over previous
//
#include <hip/hip_runtime.h>

#define N_NODES 100000
#define N_EDGES 1600000
#define D 64
#define NB 391                 // buckets of 256 rows (finalize/convert blocks)
#define R1 100096              // rowcnt slots + gctr + pad (keeps xs 16B-aligned)

__device__ __forceinline__ unsigned short f2b(float f) {
    unsigned u = __float_as_uint(f);
    u += 0x7FFF + ((u >> 16) & 1);            // round-to-nearest-even
    return (unsigned short)(u >> 16);
}
__device__ __forceinline__ float b2f(unsigned short v) {
    return __uint_as_float(((unsigned)v) << 16);
}

// ---- pass 0: zero rowcnt + gctr (kernel, not memset, for graph-capture safety) ----
__global__ void zero_kernel(int* __restrict__ p) {
    int i = blockIdx.x * blockDim.x + threadIdx.x;
    if (i < R1) p[i] = 0;
}

// ---- pass 1: degree histogram. int4 edge reads, fire-and-forget global atomics ----
__global__ void hist_kernel(const int* __restrict__ ei, int* __restrict__ rowcnt) {
    int t = blockIdx.x * blockDim.x + threadIdx.x;
    int i4 = t * 4;
    if (i4 >= N_EDGES) return;
    int4 r = *(const int4*)(ei + i4);
    int4 c = *(const int4*)(ei + N_EDGES + i4);
    if (r.x != c.x) atomicAdd(&rowcnt[r.x], 1);
    if (r.y != c.y) atomicAdd(&rowcnt[r.y], 1);
    if (r.z != c.z) atomicAdd(&rowcnt[r.z], 1);
    if (r.w != c.w) atomicAdd(&rowcnt[r.w], 1);
}

// ---- pass 2: per-bucket LDS scan -> atomic base claim -> rowstart/cursor ----
// (bucket bases claimed in arbitrary order: rowstart only needs to partition colidx)
// fused bf16 convert: xs = bf16(x * dinv)  (proven round-0 loop)
__global__ void finalize_convert_kernel(const int* __restrict__ rowcnt, int* __restrict__ gctr,
                                        int* __restrict__ rowstart, int* __restrict__ cursor,
                                        const float* __restrict__ x,
                                        unsigned short* __restrict__ xs) {
    __shared__ int sc[256];
    __shared__ float dv[256];
    __shared__ int sbase;
    int b = blockIdx.x, t = threadIdx.x;
    int row = b * 256 + t;
    int v = (row < N_NODES) ? rowcnt[row] : 0;
    sc[t] = v;
    __syncthreads();
    for (int off = 1; off < 256; off <<= 1) {       // inclusive scan of counts
        int u = (t >= off) ? sc[t - off] : 0;
        __syncthreads();
        sc[t] += u;
        __syncthreads();
    }
    if (t == 255) sbase = atomicAdd(gctr, sc[255]); // claim this bucket's run
    dv[t] = rsqrtf((float)(1 + v));                 // deg = nonself + self loop
    __syncthreads();
    int rs = sbase + sc[t] - v;                     // exclusive within bucket
    if (row < N_NODES) { rowstart[row] = rs; cursor[row] = rs; }
    int nrows = min(256, N_NODES - b * 256);
    const float4* x4 = (const float4*)x;
    ushort4* xs4 = (ushort4*)xs;
    for (int i = t; i < nrows * 16; i += 256) {     // 16 float4 per row
        int rl = i >> 4;
        float4 vv = x4[(size_t)(b * 256 + rl) * 16 + (i & 15)];
        float dd = dv[rl];
        ushort4 o;
        o.x = f2b(vv.x * dd);
        o.y = f2b(vv.y * dd);
        o.z = f2b(vv.z * dd);
        o.w = f2b(vv.w * dd);
        xs4[(size_t)(b * 256 + rl) * 16 + (i & 15)] = o;
    }
}

// ---- pass 3: place cols at final CSR slots. 4 independent atomic-returns in flight ----
__global__ void place_kernel(const int* __restrict__ ei, int* __restrict__ cursor,
                             int* __restrict__ colidx) {
    int t = blockIdx.x * blockDim.x + threadIdx.x;
    int i4 = t * 4;
    if (i4 >= N_EDGES) return;
    int4 r = *(const int4*)(ei + i4);
    int4 c = *(const int4*)(ei + N_EDGES + i4);
    int p0 = (r.x != c.x) ? atomicAdd(&cursor[r.x], 1) : -1;
    int p1 = (r.y != c.y) ? atomicAdd(&cursor[r.y], 1) : -1;
    int p2 = (r.z != c.z) ? atomicAdd(&cursor[r.z], 1) : -1;
    int p3 = (r.w != c.w) ? atomicAdd(&cursor[r.w], 1) : -1;
    if (p0 >= 0) colidx[p0] = c.x;
    if (p1 >= 0) colidx[p1] = c.y;
    if (p2 >= 0) colidx[p2] = c.z;
    if (p3 >= 0) colidx[p3] = c.w;
}

// ---- pass 4: gather. One wave per row, lane d = feature d, MLP-8 unroll ----
// (identical to the verified 44.4us kernel; dinv recomputed from cnt)
__global__ void gather_kernel(const unsigned short* __restrict__ xs,
                              const int* __restrict__ rowcnt,
                              const int* __restrict__ rowstart,
                              const int* __restrict__ colidx,
                              float* __restrict__ out) {
    int t = blockIdx.x * blockDim.x + threadIdx.x;
    int r = t >> 6;
    int d = t & 63;
    if (r >= N_NODES) return;
    int start = rowstart[r];
    int cnt = rowcnt[r];
    int end = start + cnt;
    float dr = rsqrtf((float)(1 + cnt));
    float acc = b2f(xs[r * D + d]);           // self-loop (xs already carries dinv[r])
    for (int j = start; j < end; j += 64) {
        int idx = j + d;
        int cj = 0;
        if (idx < end) cj = colidx[idx];
        int n = min(64, end - j);
        int k = 0;
        for (; k + 8 <= n; k += 8) {
            int c0 = __shfl(cj, k);
            int c1 = __shfl(cj, k + 1);
            int c2 = __shfl(cj, k + 2);
            int c3 = __shfl(cj, k + 3);
            int c4 = __shfl(cj, k + 4);
            int c5 = __shfl(cj, k + 5);
            int c6 = __shfl(cj, k + 6);
            int c7 = __shfl(cj, k + 7);
            float v0 = b2f(xs[c0 * D + d]);   // 8 independent 128B loads in flight
            float v1 = b2f(xs[c1 * D + d]);
            float v2 = b2f(xs[c2 * D + d]);
            float v3 = b2f(xs[c3 * D + d]);
            float v4 = b2f(xs[c4 * D + d]);
            float v5 = b2f(xs[c5 * D + d]);
            float v6 = b2f(xs[c6 * D + d]);
            float v7 = b2f(xs[c7 * D + d]);
            acc += ((v0 + v1) + (v2 + v3)) + ((v4 + v5) + (v6 + v7));
        }
        for (; k + 4 <= n; k += 4) {
            int c0 = __shfl(cj, k);
            int c1 = __shfl(cj, k + 1);
            int c2 = __shfl(cj, k + 2);
            int c3 = __shfl(cj, k + 3);
            float v0 = b2f(xs[c0 * D + d]);
            float v1 = b2f(xs[c1 * D + d]);
            float v2 = b2f(xs[c2 * D + d]);
            float v3 = b2f(xs[c3 * D + d]);
            acc += (v0 + v1) + (v2 + v3);
        }
        for (; k < n; k++) {
            int c = __shfl(cj, k);
            acc += b2f(xs[c * D + d]);
        }
    }
    out[r * D + d] = dr * acc;
}

extern "C" void kernel_launch(void* const* d_in, const int* in_sizes, int n_in,
                              void* d_out, int out_size, void* d_ws, size_t ws_size,
                              hipStream_t stream) {
    const float* x = (const float*)d_in[0];
    const int* ei = (const int*)d_in[1];
    float* out = (float*)d_out;

    // workspace (~20.4 MB): rowcnt+gctr | rowstart | cursor | colidx | xs
    int* rowcnt = (int*)d_ws;                         // [N_NODES] (+gctr at N_NODES, pad to R1)
    int* gctr = rowcnt + N_NODES;                     // [1]
    int* rowstart = rowcnt + R1;                      // [N_NODES]
    int* cursor = rowstart + N_NODES;                 // [N_NODES]
    int* colidx = cursor + N_NODES;                   // [N_EDGES] exact CSR, no padding
    unsigned short* xs = (unsigned short*)(colidx + N_EDGES); // [N_NODES*D], 16B-aligned

    int egrid = (N_EDGES / 4 + 255) / 256;            // 1563 blocks, 1 quad/thread

    zero_kernel<<<(R1 + 255) / 256, 256, 0, stream>>>(rowcnt);
    hist_kernel<<<egrid, 256, 0, stream>>>(ei, rowcnt);
    finalize_convert_kernel<<<NB, 256, 0, stream>>>(rowcnt, gctr, rowstart, cursor, x, xs);
    place_kernel<<<egrid, 256, 0, stream>>>(ei, cursor, colidx);
    gather_kernel<<<(N_NODES * D + 255) / 256, 256, 0, stream>>>(xs, rowcnt, rowstart, colidx, out);
}

// Round 4
// 160.100 us; speedup vs baseline: 5.1581x; 2.0816x over previous
//
#include <hip/hip_runtime.h>

#define N_NODES 100000
#define N_EDGES 1600000
#define D 64
#define NB 391                 // buckets of 256 rows
#define BCAP 4480              // bucket capacity (mean 4093, sigma 64 -> z=6; proven)
#define PBLK 512               // scatter blocks
#define TPB 512                // threads per block (scatter & sort)
#define CHUNK ((N_EDGES + PBLK - 1) / PBLK)   // 3125 edges per block
#define CURSTRIDE 32           // pad cursors to one line each

__device__ __forceinline__ unsigned short f2b(float f) {
    unsigned u = __float_as_uint(f);
    u += 0x7FFF + ((u >> 16) & 1);            // round-to-nearest-even
    return (unsigned short)(u >> 16);
}

// ---- pass 0: cursors start at each bucket's base ----
__global__ void init_cursor_kernel(int* __restrict__ cursor) {
    int b = blockIdx.x * blockDim.x + threadIdx.x;
    if (b < NB) cursor[b * CURSTRIDE] = b * BCAP;
}

// ---- pass 1: fused count+partition. LDS-staged chunk -> hist -> reserve -> write runs ----
__global__ __launch_bounds__(TPB) void scatter_direct_kernel(const int* __restrict__ ei,
                                                             int* __restrict__ cursor,
                                                             int* __restrict__ epack) {
    __shared__ int er[CHUNK];      // 12.5 KB
    __shared__ int ec[CHUNK];      // 12.5 KB
    __shared__ int h[NB];
    __shared__ int lbase[NB];
    __shared__ int lcur[NB];
    int t = threadIdx.x;
    for (int i = t; i < NB; i += TPB) h[i] = 0;
    int s = blockIdx.x * CHUNK;
    int e = min(s + CHUNK, N_EDGES);
    int n = e - s;
    for (int i = t; i < n; i += TPB) {
        er[i] = ei[s + i];
        ec[i] = ei[N_EDGES + s + i];
    }
    __syncthreads();
    for (int i = t; i < n; i += TPB) {
        int r = er[i], c = ec[i];
        if (r != c) atomicAdd(&h[r >> 8], 1);
    }
    __syncthreads();
    for (int i = t; i < NB; i += TPB) {
        lbase[i] = atomicAdd(&cursor[i * CURSTRIDE], h[i]);  // reserve contiguous run
        lcur[i] = 0;
    }
    __syncthreads();
    for (int i = t; i < n; i += TPB) {
        int r = er[i], c = ec[i];
        if (r != c) {
            int b = r >> 8;
            int p = lbase[b] + atomicAdd(&lcur[b], 1);
            epack[p] = ((r & 255) << 17) | c;    // runs pack lines in L2 -> low HBM write waste
        }
    }
}

// ---- pass 2: per-bucket LDS counting sort (in place, 512 thr) + rowinfo + fused convert ----
__global__ __launch_bounds__(TPB) void csr_sort_convert_kernel(const int* __restrict__ cursor,
                                                               int* __restrict__ epack,
                                                               int2* __restrict__ rowinfo,
                                                               const float* __restrict__ x,
                                                               unsigned short* __restrict__ xs) {
    __shared__ int ebuf[BCAP];     // 17.9 KB staging of the bucket's edges
    __shared__ int h[256];
    __shared__ int sc[256];
    __shared__ int cur[256];
    __shared__ float dv[256];
    int b = blockIdx.x;
    int t = threadIdx.x;
    int base = b * BCAP;
    int n = min(cursor[b * CURSTRIDE] - base, BCAP);
    for (int i = t; i < n; i += TPB) ebuf[i] = epack[base + i];
    if (t < 256) h[t] = 0;
    __syncthreads();
    for (int i = t; i < n; i += TPB) atomicAdd(&h[ebuf[i] >> 17], 1);
    __syncthreads();
    int v = 0;
    if (t < 256) { v = h[t]; sc[t] = v; }
    __syncthreads();
    for (int off = 1; off < 256; off <<= 1) {      // inclusive scan over 256 counts
        int u = (t < 256 && t >= off) ? sc[t - off] : 0;
        __syncthreads();
        if (t < 256) sc[t] += u;
        __syncthreads();
    }
    if (t < 256) {
        int excl = sc[t] - v;
        int row = b * 256 + t;
        if (row < N_NODES) rowinfo[row] = make_int2(base + excl, v);
        dv[t] = rsqrtf((float)(1 + v));
        cur[t] = excl;
    }
    __syncthreads();
    for (int i = t; i < n; i += TPB) {             // scatter LDS -> sorted, in place in epack
        int p = ebuf[i];
        int pos = atomicAdd(&cur[p >> 17], 1);
        epack[base + pos] = (p & 0x1FFFF) << 7;    // pre-scaled: byte offset of row in xs
    }
    // fused convert for this bucket's rows: xs = bf16(x * dinv)
    int nrows = min(256, N_NODES - b * 256);
    const float4* x4 = (const float4*)x;
    ushort4* xs4 = (ushort4*)xs;
    for (int i = t; i < nrows * 16; i += TPB) {    // 16 float4 per row
        int rl = i >> 4;
        float4 vv = x4[(size_t)(b * 256 + rl) * 16 + (i & 15)];
        float dd = dv[rl];
        ushort4 o;
        o.x = f2b(vv.x * dd);
        o.y = f2b(vv.y * dd);
        o.z = f2b(vv.z * dd);
        o.w = f2b(vv.w * dd);
        xs4[(size_t)(b * 256 + rl) * 16 + (i & 15)] = o;
    }
}

// ---- pass 3: gather. One wave per row; lane = (half, feature-pair); halves take
// interleaved (even/odd) edges -> 2 edges (2 lines) per wave load, half the shfl/addr work.
// ALL loops wave-uniform: the tail clamps the shfl source lane and predicates the add
// (shfl from an inactive lane is undefined -- the round-3 bug). ----
__global__ __launch_bounds__(256) void gather_kernel(const unsigned short* __restrict__ xs,
                                                     const int2* __restrict__ rowinfo,
                                                     const int* __restrict__ colidx,
                                                     float* __restrict__ out) {
    int t = blockIdx.x * blockDim.x + threadIdx.x;
    int r = t >> 6;
    int lane = t & 63;
    if (r >= N_NODES) return;                      // wave-uniform exit
    int lp = lane & 31;            // feature pair: feats 2lp, 2lp+1
    int hf = lane >> 5;            // which half: takes edges 2k+hf
    int lpo = lp << 2;             // byte offset of the pair within a row
    int2 ri = rowinfo[r];
    int start = ri.x;
    int end = start + ri.y;
    float dr = rsqrtf((float)(1 + ri.y));
    const char* xsb = (const char*)xs;
    float ax = 0.0f, ay = 0.0f;
    if (hf == 0) {                 // self-loop term (xs already carries dinv[r])
        unsigned v = *(const unsigned*)(xsb + (((size_t)r) << 7) + lpo);
        ax = __uint_as_float(v << 16);
        ay = __uint_as_float(v & 0xFFFF0000u);
    }
    for (int j = start; j < end; j += 64) {
        int idx = j + lane;
        int cj = (idx < end) ? colidx[idx] : 0;    // coalesced tile of pre-scaled cols
        int n = min(64, end - j);
        int k = 0;
        for (; 2 * (k + 8) <= n; k += 8) {         // uniform condition, all lanes active
            int s0 = __shfl(cj, 2 * k + hf);
            int s1 = __shfl(cj, 2 * k + 2 + hf);
            int s2 = __shfl(cj, 2 * k + 4 + hf);
            int s3 = __shfl(cj, 2 * k + 6 + hf);
            int s4 = __shfl(cj, 2 * k + 8 + hf);
            int s5 = __shfl(cj, 2 * k + 10 + hf);
            int s6 = __shfl(cj, 2 * k + 12 + hf);
            int s7 = __shfl(cj, 2 * k + 14 + hf);
            unsigned v0 = *(const unsigned*)(xsb + (unsigned)(s0 + lpo));  // 16 lines in flight
            unsigned v1 = *(const unsigned*)(xsb + (unsigned)(s1 + lpo));
            unsigned v2 = *(const unsigned*)(xsb + (unsigned)(s2 + lpo));
            unsigned v3 = *(const unsigned*)(xsb + (unsigned)(s3 + lpo));
            unsigned v4 = *(const unsigned*)(xsb + (unsigned)(s4 + lpo));
            unsigned v5 = *(const unsigned*)(xsb + (unsigned)(s5 + lpo));
            unsigned v6 = *(const unsigned*)(xsb + (unsigned)(s6 + lpo));
            unsigned v7 = *(const unsigned*)(xsb + (unsigned)(s7 + lpo));
            float a0 = __uint_as_float(v0 << 16), b0 = __uint_as_float(v0 & 0xFFFF0000u);
            float a1 = __uint_as_float(v1 << 16), b1 = __uint_as_float(v1 & 0xFFFF0000u);
            float a2 = __uint_as_float(v2 << 16), b2 = __uint_as_float(v2 & 0xFFFF0000u);
            float a3 = __uint_as_float(v3 << 16), b3 = __uint_as_float(v3 & 0xFFFF0000u);
            float a4 = __uint_as_float(v4 << 16), b4 = __uint_as_float(v4 & 0xFFFF0000u);
            float a5 = __uint_as_float(v5 << 16), b5 = __uint_as_float(v5 & 0xFFFF0000u);
            float a6 = __uint_as_float(v6 << 16), b6 = __uint_as_float(v6 & 0xFFFF0000u);
            float a7 = __uint_as_float(v7 << 16), b7 = __uint_as_float(v7 & 0xFFFF0000u);
            ax += ((a0 + a1) + (a2 + a3)) + ((a4 + a5) + (a6 + a7));
            ay += ((b0 + b1) + (b2 + b3)) + ((b4 + b5) + (b6 + b7));
        }
        for (; 2 * (k + 4) <= n; k += 4) {         // uniform condition
            int s0 = __shfl(cj, 2 * k + hf);
            int s1 = __shfl(cj, 2 * k + 2 + hf);
            int s2 = __shfl(cj, 2 * k + 4 + hf);
            int s3 = __shfl(cj, 2 * k + 6 + hf);
            unsigned v0 = *(const unsigned*)(xsb + (unsigned)(s0 + lpo));
            unsigned v1 = *(const unsigned*)(xsb + (unsigned)(s1 + lpo));
            unsigned v2 = *(const unsigned*)(xsb + (unsigned)(s2 + lpo));
            unsigned v3 = *(const unsigned*)(xsb + (unsigned)(s3 + lpo));
            float a0 = __uint_as_float(v0 << 16), b0 = __uint_as_float(v0 & 0xFFFF0000u);
            float a1 = __uint_as_float(v1 << 16), b1 = __uint_as_float(v1 & 0xFFFF0000u);
            float a2 = __uint_as_float(v2 << 16), b2 = __uint_as_float(v2 & 0xFFFF0000u);
            float a3 = __uint_as_float(v3 << 16), b3 = __uint_as_float(v3 & 0xFFFF0000u);
            ax += (a0 + a1) + (a2 + a3);
            ay += (b0 + b1) + (b2 + b3);
        }
        for (; 2 * k < n; k++) {                   // UNIFORM tail: all lanes run the shfl
            int src = 2 * k + hf;
            int s0 = __shfl(cj, (src < n) ? src : (n - 1));  // clamp: valid source lane
            unsigned v0 = *(const unsigned*)(xsb + (unsigned)(s0 + lpo));
            if (src < n) {                         // predicate the accumulate only
                ax += __uint_as_float(v0 << 16);
                ay += __uint_as_float(v0 & 0xFFFF0000u);
            }
        }
    }
    ax += __shfl_xor(ax, 32);                      // combine halves
    ay += __shfl_xor(ay, 32);
    if (hf == 0) {
        float2 o;
        o.x = dr * ax;
        o.y = dr * ay;
        ((float2*)out)[(size_t)r * 32 + lp] = o;   // 256B coalesced per row
    }
}

extern "C" void kernel_launch(void* const* d_in, const int* in_sizes, int n_in,
                              void* d_out, int out_size, void* d_ws, size_t ws_size,
                              hipStream_t stream) {
    const float* x = (const float*)d_in[0];
    const int* ei = (const int*)d_in[1];
    float* out = (float*)d_out;

    // workspace (~20.7 MB): cursor | rowinfo | epack | xs
    int* cursor = (int*)d_ws;                              // [NB*CURSTRIDE] = 50 KB
    int2* rowinfo = (int2*)(cursor + NB * CURSTRIDE);      // [N_NODES] (start, cnt)
    int* epack = (int*)(rowinfo + N_NODES);                // [NB*BCAP], sorted in place
    unsigned short* xs = (unsigned short*)(epack + NB * BCAP); // [N_NODES*D]

    init_cursor_kernel<<<(NB + 255) / 256, 256, 0, stream>>>(cursor);
    scatter_direct_kernel<<<PBLK, TPB, 0, stream>>>(ei, cursor, epack);
    csr_sort_convert_kernel<<<NB, TPB, 0, stream>>>(cursor, epack, rowinfo, x, xs);
    gather_kernel<<<(N_NODES * D + 255) / 256, 256, 0, stream>>>(xs, rowinfo, epack, out);
}